// Round 8
// baseline (324.603 us; speedup 1.0000x reference)
//
#include <hip/hip_runtime.h>
#include <cstddef>

// ============================================================================
// VLSTM via bf16 MFMA, R12: fix the register budget (launch_bounds(512,1)).
//  - ROOT CAUSE (R9-R11): __launch_bounds__ 2nd arg acts as min BLOCKS/CU
//    (CUDA semantics): (512,2) capped VGPR at 128 for a 2-blocks/CU
//    co-residency that never happens (LDS-bound to 1 block/CU). Every small
//    register add since R8 spilled to scratch (+5-14 MB FETCH/WRITE).
//  - (512,1): 256-VGPR budget, occupancy unchanged (2 waves/SIMD, pool fits
//    2x256). Slack spent on: biasv as MFMA-C (kb=0) [-128 VALU adds/wave/
//    step, R7-proven], hr in 32-bit regs (no subword merge), swizzle kept
//    (conflicts 5.24M->786K, now spill-free), deeper compiler ILP in ACT.
//  - Structure = R8: MT=128, GRID=256, single round, A dbuf, 1 barrier/step,
//    reg-resident weights, ballot mask, direct OPROJ store, LDS epilogues.
// ============================================================================

typedef __attribute__((ext_vector_type(8))) short  s16x8;   // 8 x bf16
typedef __attribute__((ext_vector_type(4))) float  f32x4;

namespace {
constexpr int T_STEPS = 20;
constexpr int NN      = 32768;
constexpr int D_EMB   = 64;
constexpr int D_H     = 128;
constexpr int D_OUT   = 5;
constexpr int G4      = 512;
constexpr int MT      = 128;                  // nodes per block
constexpr int BLOCK   = 512;
constexpr int GRID    = NN / MT;              // 256 blocks = 256 CUs
constexpr int RT_N    = MT / 16;              // 8 row-tiles
constexpr int WP_ELEMS   = 8 * 4 * 6 * 64 * 8;
constexpr int WOUT_ELEMS = 4 * 64 * 8;
constexpr int A_ELEMS    = RT_N * 6 * 64 * 8;   // 24576 shorts = 48 KB / buf
constexpr float LOG2E = 1.4426950408889634f;
constexpr float AM4   = -4.0f * LOG2E;
constexpr float AP2   =  2.0f * LOG2E;
constexpr float CINV  = 0.34657359027997264f;   // 1/(2*log2e)
constexpr size_t OFF_H = (size_t)T_STEPS * NN * D_OUT;
constexpr size_t OFF_C = OFF_H + (size_t)NN * D_H;
}

__device__ __forceinline__ unsigned short f2bf(float x) {
    unsigned u = __float_as_uint(x);
    u = (u + 0x7FFFu + ((u >> 16) & 1u)) >> 16;     // RNE
    return (unsigned short)u;
}
__device__ __forceinline__ unsigned short f2bf_hw(float x) {
    __bf16 b = (__bf16)x;
    union { __bf16 b; unsigned short u; } cv;
    cv.b = b;
    return cv.u;
}
__device__ __forceinline__ float bf2f(unsigned short h) {
    return __uint_as_float(((unsigned)h) << 16);
}
__device__ __forceinline__ float exp2f_fast(float x) {
#if __has_builtin(__builtin_amdgcn_exp2f)
    return __builtin_amdgcn_exp2f(x);
#else
    return __expf(x * 0.6931471805599453f);
#endif
}
__device__ __forceinline__ float sig_pre(float a) {   // sigmoid, a = -x*log2e
    return __builtin_amdgcn_rcpf(1.0f + exp2f_fast(a));
}

// ----------------------------------------------------------------------------
__global__ void prepack_kernel(const float* __restrict__ W_ih,
                               const float* __restrict__ b_ih,
                               const float* __restrict__ W_hh,
                               const float* __restrict__ b_hh,
                               const float* __restrict__ W_out,
                               unsigned short* __restrict__ Wp,
                               unsigned short* __restrict__ WoutF,
                               float* __restrict__ b_sum) {
    int idx = blockIdx.x * blockDim.x + threadIdx.x;
    if (idx < WP_ELEMS) {
        int j    = idx & 7;
        int L    = (idx >> 3) & 63;
        int rest = idx >> 9;
        int kb   = rest % 6;
        int gw   = rest / 6;
        int g    = gw & 3, w = gw >> 2;
        int k    = kb * 32 + (L >> 4) * 8 + j;
        int col  = g * D_H + w * 16 + (L & 15);
        float v  = (k < D_EMB) ? W_ih[k * G4 + col] : W_hh[(k - D_EMB) * G4 + col];
        float s  = (g == 2) ? (2.0f * LOG2E) : (-LOG2E);
        Wp[idx] = f2bf(v * s);
    } else if (idx < WP_ELEMS + WOUT_ELEMS) {
        int i2 = idx - WP_ELEMS;
        int j = i2 & 7, L = (i2 >> 3) & 63, kb2 = i2 >> 9;
        int k = kb2 * 32 + (L >> 4) * 8 + j;
        int n = L & 15;
        WoutF[i2] = (n < D_OUT) ? f2bf(W_out[k * D_OUT + n]) : (unsigned short)0;
    }
    if (idx < G4) {
        int g = idx / D_H;
        float s = (g == 2) ? (2.0f * LOG2E) : (-LOG2E);
        b_sum[idx] = (b_ih[idx] + b_hh[idx]) * s;
    }
}

// ----------------------------------------------------------------------------
__global__ __launch_bounds__(BLOCK, 1) void vlstm_kernel(
    const float* __restrict__ nodes,   // [T][N][2]
    const int*   __restrict__ mask,    // [T][N]
    const float* __restrict__ h0,      // [N][128]
    const float* __restrict__ c0,      // [N][128]
    const float* __restrict__ W_embed, // [2][64]
    const float* __restrict__ b_embed, // [64]
    const float* __restrict__ b_out,   // [5]
    const unsigned short* __restrict__ Wp,
    const unsigned short* __restrict__ WoutF,
    const float* __restrict__ b_sum,
    float* __restrict__ out)
{
    __shared__ __align__(16) unsigned short A[2][A_ELEMS];   // 96 KB dbuf
    __shared__ __align__(16) unsigned short WoS[WOUT_ELEMS]; // 4 KB
    __shared__ float We_s[2 * D_EMB];
    __shared__ float be_s[D_EMB];
    __shared__ __align__(16) unsigned long long msk64[2][2];

    const int tid  = threadIdx.x;
    const int wave = tid >> 6;
    const int L    = tid & 63;
    const int quad = L >> 4;
    const int l15  = L & 15;
    const int n_base = blockIdx.x * MT;

    // swizzled lane base for all A-frag reads (GEMM + OPROJ), in shorts
    const int Lsw = (L * 8) ^ (((L >> 3) & 7) << 3);

    // ---- gate weights -> registers, once (96 VGPR/wave) ----
    const unsigned short* wbase = Wp + (size_t)wave * (4 * 6 * 64 * 8);
    s16x8 Bf[4][6];
    #pragma unroll
    for (int g = 0; g < 4; g++)
        #pragma unroll
        for (int kb = 0; kb < 6; kb++)
            Bf[g][kb] = *(const s16x8*)(wbase + ((g * 6 + kb) * 64 + L) * 8);

    const int u_lane = wave * 16 + l15;
    f32x4 biasv[4];
    #pragma unroll
    for (int g = 0; g < 4; g++) {
        float b = b_sum[g * D_H + u_lane];
        biasv[g] = (f32x4){b, b, b, b};
    }
    const float bo = (l15 < D_OUT) ? b_out[l15] : 0.0f;

    // per-thread A h-row write geometry (+ swizzle XOR, constant per thread)
    const int kb_u = 2 + (u_lane >> 5);
    const int fl   = ((u_lane >> 3) & 3) * 16 + quad * 4;
    const int j_u  = u_lane & 7;
    const int swzw = ((fl >> 3) & 7) << 3;

    // ---- one-time LDS staging ----
    for (int i = tid; i < 3 * D_EMB; i += BLOCK) {
        if (i < 2 * D_EMB) We_s[i] = W_embed[i];
        else               be_s[i - 2 * D_EMB] = b_embed[i - 2 * D_EMB];
    }
    for (int i = tid; i < WOUT_ELEMS; i += BLOCK) WoS[i] = WoutF[i];

    // ---- h, c -> registers (c as cL = 2c*log2e); h -> A[0] h-rows ----
    float    cL[RT_N][4];
    unsigned hr[RT_N][4];                        // bf16 in low 16 bits
    #pragma unroll
    for (int rt = 0; rt < RT_N; rt++)
        #pragma unroll
        for (int r = 0; r < 4; r++) {
            int m = rt * 16 + quad * 4 + r;
            cL[rt][r] = AP2 * c0[(size_t)(n_base + m) * D_H + u_lane];
            hr[rt][r] = f2bf_hw(h0[(size_t)(n_base + m) * D_H + u_lane]);
            A[0][((((rt * 6 + kb_u) * 64 + fl + r) * 8) + j_u) ^ swzw] =
                (unsigned short)hr[rt][r];
        }

    // ---- emb mapping: 4 threads/node, 16 emb dims each (2 x b128) ----
    const int node_e = tid >> 2;
    const int eb2    = tid & 3;
    int idx_e[2];
    #pragma unroll
    for (int s = 0; s < 2; s++) {
        int e0 = eb2 * 16 + s * 8;
        int base = (((node_e >> 4) * 6 + (e0 >> 5)) * 64 +
                    ((e0 >> 3) & 3) * 16 + (node_e & 15)) * 8;
        int t_e  = ((((e0 >> 3) & 3) * 2 + ((node_e & 15) >> 3)) & 7) << 3;
        idx_e[s] = base ^ t_e;
    }

#define EMB_WRITE(AW, XV) do {                                                 \
    _Pragma("unroll")                                                          \
    for (int s = 0; s < 2; s++) {                                              \
        s16x8 ev;                                                              \
        _Pragma("unroll")                                                      \
        for (int j = 0; j < 8; j++) {                                          \
            int e = eb2 * 16 + s * 8 + j;                                      \
            float v = fmaf((XV).x, We_s[e], fmaf((XV).y, We_s[D_EMB + e], be_s[e])); \
            ev[j] = (short)f2bf_hw(fmaxf(v, 0.0f));                            \
        }                                                                      \
        *(s16x8*)((AW) + idx_e[s]) = ev;                                       \
    } } while (0)

    // ---- emb(0) + mask(0) -> A[0] ----
    {
        float2 x0 = *(const float2*)(nodes + (size_t)(n_base + node_e) * 2);
        EMB_WRITE(A[0], x0);
        int lm0 = (tid < MT) ? mask[n_base + tid] : 0;
        if (wave < 2) {
            unsigned long long bm = __ballot(lm0 != 0);
            if (L == 0) msk64[0][wave] = bm;
        }
    }
    __syncthreads();   // prologue barrier

// GEMM of one row-tile into acc slot rt&1; kb=0 MFMA uses biasv as C
#define GEMM_RT(rt) do {                                                       \
    {   s16x8 af0 = *(const s16x8*)(Ar + ((rt) * 6 + 0) * 512 + Lsw);          \
        _Pragma("unroll")                                                      \
        for (int g = 0; g < 4; g++)                                            \
            acc[(rt) & 1][g] = __builtin_amdgcn_mfma_f32_16x16x32_bf16(        \
                af0, Bf[g][0], biasv[g], 0, 0, 0); }                           \
    _Pragma("unroll")                                                          \
    for (int kb = 1; kb < 6; kb++) {                                           \
        s16x8 af = *(const s16x8*)(Ar + ((rt) * 6 + kb) * 512 + Lsw);          \
        _Pragma("unroll")                                                      \
        for (int g = 0; g < 4; g++)                                            \
            acc[(rt) & 1][g] = __builtin_amdgcn_mfma_f32_16x16x32_bf16(        \
                af, Bf[g][kb], acc[(rt) & 1][g], 0, 0, 0); }                   \
} while (0)

// Activations + state update + unconditional h-write (slot rt&1 freed after)
#define ACT_RT(rt, MW) do {                                                    \
    unsigned nib = (unsigned)((MW) >> (((rt) & 3) * 16 + quad * 4)) & 0xFu;    \
    _Pragma("unroll")                                                          \
    for (int r = 0; r < 4; r++) {                                              \
        float gi = sig_pre(acc[(rt) & 1][0][r]);                               \
        float gf = sig_pre(acc[(rt) & 1][1][r]);                               \
        float rg = sig_pre(acc[(rt) & 1][2][r]);                               \
        float go = sig_pre(acc[(rt) & 1][3][r]);                               \
        float ggL = fmaf(AM4, rg, AP2);            /* 2*log2e*tanh(g) */       \
        float cnL = fmaf(gf, cL[rt][r], gi * ggL); /* 2*log2e*c_new   */       \
        float rr  = __builtin_amdgcn_rcpf(1.0f + exp2f_fast(cnL));             \
        float hv  = go * fmaf(-2.0f, rr, 1.0f);    /* o*tanh(c_new)   */       \
        unsigned hb = f2bf_hw(hv);                                             \
        if ((nib >> r) & 1u) { cL[rt][r] = cnL; hr[rt][r] = hb; }              \
        Aw[(((((rt) * 6 + kb_u) * 64 + fl + r) * 8) + j_u) ^ swzw] =           \
            (unsigned short)hr[rt][r];                                         \
    } } while (0)

// out-proj for time TIDX from buffer ARP (h rows), mask words MPA/MPB (regs),
// direct masked global store: wave covers contiguous 320B.
#define OPROJ(ARP, TIDX, MPA, MPB) do {                                        \
    f32x4 ao = (f32x4){0.f, 0.f, 0.f, 0.f};                                    \
    _Pragma("unroll")                                                          \
    for (int kb2 = 0; kb2 < 4; kb2++) {                                        \
        s16x8 af = *(const s16x8*)((ARP) + (wave * 6 + 2 + kb2) * 512 + Lsw);  \
        s16x8 wf = *(const s16x8*)(WoS + (kb2 * 64 + L) * 8);                  \
        ao = __builtin_amdgcn_mfma_f32_16x16x32_bf16(af, wf, ao, 0, 0, 0);     \
    }                                                                          \
    if (l15 < D_OUT) {                                                         \
        unsigned long long Mw = (wave < 4) ? (MPA) : (MPB);                    \
        unsigned nib = (unsigned)(Mw >> ((wave & 3) * 16 + quad * 4)) & 0xFu;  \
        float* ob = out + ((size_t)(TIDX) * NN + n_base) * D_OUT + l15;        \
        _Pragma("unroll")                                                      \
        for (int r = 0; r < 4; r++) {                                          \
            int node = wave * 16 + quad * 4 + r;                               \
            ob[node * D_OUT] = ((nib >> r) & 1u) ? (ao[r] + bo) : 0.0f;        \
        }                                                                      \
    } } while (0)

    unsigned long long Mp0 = 0, Mp1 = 0;

    for (int t = 0; t < T_STEPS; t++) {
        unsigned short* __restrict__ Ar = A[t & 1];
        unsigned short* __restrict__ Aw = A[(t + 1) & 1];

        const unsigned long long M0 = msk64[t & 1][0];
        const unsigned long long M1 = msk64[t & 1][1];

        // prefetch x(t+1)/mask(t+1): consumed late
        float2 xv = make_float2(0.0f, 0.0f);
        int    lm = 0;
        if (t + 1 < T_STEPS) {
            xv = *(const float2*)(nodes + ((size_t)(t + 1) * NN + n_base + node_e) * 2);
            if (tid < MT) lm = mask[(size_t)(t + 1) * NN + n_base + tid];
        }

        f32x4 acc[2][4];
        GEMM_RT(0);
        GEMM_RT(1);
        ACT_RT(0, M0);
        GEMM_RT(2);
        ACT_RT(1, M0);
        GEMM_RT(3);
        ACT_RT(2, M0);
        if (t > 0) OPROJ(Ar, t - 1, Mp0, Mp1);
        ACT_RT(3, M0);
        GEMM_RT(4);
        GEMM_RT(5);
        ACT_RT(4, M1);
        GEMM_RT(6);
        ACT_RT(5, M1);
        GEMM_RT(7);
        ACT_RT(6, M1);
        if (t + 1 < T_STEPS) {
            EMB_WRITE(Aw, xv);
            if (wave < 2) {
                unsigned long long bm = __ballot(lm != 0);
                if (L == 0) msk64[(t + 1) & 1][wave] = bm;
            }
        }
        ACT_RT(7, M1);

        Mp0 = M0; Mp1 = M1;
        __syncthreads();   // THE barrier: nothing runs after it this step
    }

    // ---- epilogue: A[0] holds h(19); Mp = M(19) ----
    OPROJ(A[0], T_STEPS - 1, Mp0, Mp1);

    // h_fin: coalesced from A[0] (swizzle-aware)
    for (int i = tid; i < MT * D_H; i += BLOCK) {
        int node = i >> 7, u = i & 127;
        int base = (((node >> 4) * 6 + 2 + (u >> 5)) * 64 +
                    ((u >> 3) & 3) * 16 + (node & 15)) * 8 + (u & 7);
        int t_f  = ((((u >> 3) & 3) * 2 + ((node & 15) >> 3)) & 7) << 3;
        out[OFF_H + (size_t)(n_base + node) * D_H + u] = bf2f(A[0][base ^ t_f]);
    }

    // c_fin: LDS staging (stride 129), coalesced copy
    __syncthreads();                    // all A reads done
    float* cs = (float*)A;              // 128*129*4 = 66 KB of the 96 KB
    #pragma unroll
    for (int rt = 0; rt < RT_N; rt++)
        #pragma unroll
        for (int r = 0; r < 4; r++) {
            int m = rt * 16 + quad * 4 + r;
            cs[m * 129 + u_lane] = CINV * cL[rt][r];
        }
    __syncthreads();
    for (int i = tid; i < MT * D_H; i += BLOCK) {
        int node = i >> 7, u = i & 127;
        out[OFF_C + (size_t)(n_base + node) * D_H + u] = cs[node * 129 + u];
    }

#undef EMB_WRITE
#undef GEMM_RT
#undef ACT_RT
#undef OPROJ
}

extern "C" void kernel_launch(void* const* d_in, const int* in_sizes, int n_in,
                              void* d_out, int out_size, void* d_ws, size_t ws_size,
                              hipStream_t stream) {
    const float* nodes   = (const float*)d_in[0];
    const int*   mask    = (const int*)  d_in[1];
    const float* h0      = (const float*)d_in[2];
    const float* c0      = (const float*)d_in[3];
    const float* W_embed = (const float*)d_in[4];
    const float* b_embed = (const float*)d_in[5];
    const float* W_ih    = (const float*)d_in[6];
    const float* b_ih    = (const float*)d_in[7];
    const float* W_hh    = (const float*)d_in[8];
    const float* b_hh    = (const float*)d_in[9];
    const float* W_out   = (const float*)d_in[10];
    const float* b_out   = (const float*)d_in[11];
    float* out = (float*)d_out;

    unsigned short* Wp    = (unsigned short*)d_ws;
    unsigned short* WoutF = Wp + WP_ELEMS;
    float*          b_sum = (float*)(WoutF + WOUT_ELEMS);

    prepack_kernel<<<(WP_ELEMS + WOUT_ELEMS + 255) / 256, 256, 0, stream>>>(
        W_ih, b_ih, W_hh, b_hh, W_out, Wp, WoutF, b_sum);

    vlstm_kernel<<<GRID, BLOCK, 0, stream>>>(
        nodes, mask, h0, c0, W_embed, b_embed, b_out, Wp, WoutF, b_sum, out);
}

// Round 10
// 272.781 us; speedup vs baseline: 1.1900x; 1.1900x over previous
//
#include <hip/hip_runtime.h>
#include <cstddef>

// ============================================================================
// VLSTM via bf16 MFMA, R14: active-node compaction (R13 + OOB fix).
//  - R13 audit: lst[] slots >= nA were uninitialized; ACT_RT read
//    cS[orig*132+...] unconditionally -> LDS OOB with garbage orig (<=255).
//    Fix: list build writes ALL 64 slots (actives first, inactives after:
//    bijection onto [0,64)) so every lst entry is a valid node id.
//  - Theory unchanged: ~50% of gates/ACT/out work is on masked-out nodes and
//    discarded by the reference. Compact active nodes per step into
//    ceil(nA/16) MFMA row-tiles (avg ~2.5 of 4). Trans count ~halved.
//  - State in LDS (compact position != owner thread): cS[64][132] f32 scaled,
//    hS[64][130] bf16. Per-step active list via wave0 ballot+popcount (dbuf).
//  - Step: X{compact GEMM/ACT interleave + OPROJ(t-1) on compact hNewC +
//    wave0 list(t+1)} B1 Y{out-store(t-1) dense, emb(t+1)+h-gather -> A(t+1)}
//    B2. Active-path math bit-identical to R8.
// ============================================================================

typedef __attribute__((ext_vector_type(8))) short  s16x8;   // 8 x bf16
typedef __attribute__((ext_vector_type(4))) float  f32x4;

namespace {
constexpr int T_STEPS = 20;
constexpr int NN      = 32768;
constexpr int D_EMB   = 64;
constexpr int D_H     = 128;
constexpr int D_OUT   = 5;
constexpr int G4      = 512;
constexpr int MT      = 64;                   // nodes per block
constexpr int BLOCK   = 512;
constexpr int GRID    = NN / MT;              // 512 blocks, 2 rounds
constexpr int WP_ELEMS   = 8 * 4 * 6 * 64 * 8;
constexpr int WOUT_ELEMS = 4 * 64 * 8;
constexpr float LOG2E = 1.4426950408889634f;
constexpr float AM4   = -4.0f * LOG2E;
constexpr float AP2   =  2.0f * LOG2E;
constexpr float CINV  = 0.34657359027997264f;   // 1/(2*log2e)
constexpr size_t OFF_H = (size_t)T_STEPS * NN * D_OUT;
constexpr size_t OFF_C = OFF_H + (size_t)NN * D_H;
}

__device__ __forceinline__ unsigned short f2bf(float x) {
    unsigned u = __float_as_uint(x);
    u = (u + 0x7FFFu + ((u >> 16) & 1u)) >> 16;     // RNE
    return (unsigned short)u;
}
__device__ __forceinline__ unsigned short f2bf_hw(float x) {
    __bf16 b = (__bf16)x;
    union { __bf16 b; unsigned short u; } cv;
    cv.b = b;
    return cv.u;
}
__device__ __forceinline__ float bf2f(unsigned short h) {
    return __uint_as_float(((unsigned)h) << 16);
}
__device__ __forceinline__ float exp2f_fast(float x) {
#if __has_builtin(__builtin_amdgcn_exp2f)
    return __builtin_amdgcn_exp2f(x);
#else
    return __expf(x * 0.6931471805599453f);
#endif
}
__device__ __forceinline__ float sig_pre(float a) {   // sigmoid, a = -x*log2e
    return __builtin_amdgcn_rcpf(1.0f + exp2f_fast(a));
}

// ----------------------------------------------------------------------------
__global__ void prepack_kernel(const float* __restrict__ W_ih,
                               const float* __restrict__ b_ih,
                               const float* __restrict__ W_hh,
                               const float* __restrict__ b_hh,
                               const float* __restrict__ W_out,
                               unsigned short* __restrict__ Wp,
                               unsigned short* __restrict__ WoutF,
                               float* __restrict__ b_sum) {
    int idx = blockIdx.x * blockDim.x + threadIdx.x;
    if (idx < WP_ELEMS) {
        int j    = idx & 7;
        int L    = (idx >> 3) & 63;
        int rest = idx >> 9;
        int kb   = rest % 6;
        int gw   = rest / 6;
        int g    = gw & 3, w = gw >> 2;
        int k    = kb * 32 + (L >> 4) * 8 + j;
        int col  = g * D_H + w * 16 + (L & 15);
        float v  = (k < D_EMB) ? W_ih[k * G4 + col] : W_hh[(k - D_EMB) * G4 + col];
        float s  = (g == 2) ? (2.0f * LOG2E) : (-LOG2E);
        Wp[idx] = f2bf(v * s);
    } else if (idx < WP_ELEMS + WOUT_ELEMS) {
        int i2 = idx - WP_ELEMS;
        int j = i2 & 7, L = (i2 >> 3) & 63, kb2 = i2 >> 9;
        int k = kb2 * 32 + (L >> 4) * 8 + j;
        int n = L & 15;
        WoutF[i2] = (n < D_OUT) ? f2bf(W_out[k * D_OUT + n]) : (unsigned short)0;
    }
    if (idx < G4) {
        int g = idx / D_H;
        float s = (g == 2) ? (2.0f * LOG2E) : (-LOG2E);
        b_sum[idx] = (b_ih[idx] + b_hh[idx]) * s;
    }
}

// ----------------------------------------------------------------------------
__global__ __launch_bounds__(BLOCK, 1) void vlstm_kernel(
    const float* __restrict__ nodes,   // [T][N][2]
    const int*   __restrict__ mask,    // [T][N]
    const float* __restrict__ h0,      // [N][128]
    const float* __restrict__ c0,      // [N][128]
    const float* __restrict__ W_embed, // [2][64]
    const float* __restrict__ b_embed, // [64]
    const float* __restrict__ b_out,   // [5]
    const unsigned short* __restrict__ Wp,
    const unsigned short* __restrict__ WoutF,
    const float* __restrict__ b_sum,
    float* __restrict__ out)
{
    __shared__ __align__(16) unsigned short Acp[2][4 * 6 * 512];   // 48 KB
    __shared__ __align__(16) unsigned short hNewC[2][4 * 4 * 512]; // 32 KB
    __shared__ float          cS[MT * 132];                        // 33.8 KB
    __shared__ unsigned short hS[MT * 130];                        // 16.6 KB
    __shared__ float          st_o[2][MT * D_OUT];                 // 2.5 KB
    __shared__ __align__(16) unsigned short WoS[WOUT_ELEMS];       // 4 KB
    __shared__ float We_s[2 * D_EMB];
    __shared__ float be_s[D_EMB];
    __shared__ unsigned long long msk64[2];
    __shared__ unsigned char lst[2][MT];
    __shared__ int nAs[2];

    const int tid  = threadIdx.x;
    const int wave = tid >> 6;
    const int L    = tid & 63;
    const int quad = L >> 4;
    const int l15  = L & 15;
    const int n_base = blockIdx.x * MT;
    const int u_lane = wave * 16 + l15;

    // ---- gate weights -> registers, once (96 VGPR/wave) ----
    const unsigned short* wbase = Wp + (size_t)wave * (4 * 6 * 64 * 8);
    s16x8 Bf[4][6];
    #pragma unroll
    for (int g = 0; g < 4; g++)
        #pragma unroll
        for (int kb = 0; kb < 6; kb++)
            Bf[g][kb] = *(const s16x8*)(wbase + ((g * 6 + kb) * 64 + L) * 8);

    float bias[4];
    #pragma unroll
    for (int g = 0; g < 4; g++) bias[g] = b_sum[g * D_H + u_lane];
    const float bo = (l15 < D_OUT) ? b_out[l15] : 0.0f;

    // per-thread geometry
    const int kbu2 = u_lane >> 5;                               // h kb-block 0..3
    const int flg  = ((u_lane >> 3) & 3) * 128 + (u_lane & 7);  // gather frag base
    const int j_u  = u_lane & 7;
    const int flh  = ((u_lane >> 3) & 3) * 128 + quad * 32;     // hNewC base
    const int node_e = tid >> 3;
    const int eb     = tid & 7;

    // ---- one-time LDS staging ----
    for (int i = tid; i < 3 * D_EMB; i += BLOCK) {
        if (i < 2 * D_EMB) We_s[i] = W_embed[i];
        else               be_s[i - 2 * D_EMB] = b_embed[i - 2 * D_EMB];
    }
    for (int i = tid; i < WOUT_ELEMS; i += BLOCK) WoS[i] = WoutF[i];

    // ---- state load: cS (scaled), hS (bf16) ----
    for (int i = tid; i < MT * D_H; i += BLOCK) {
        int node = i >> 7, u = i & 127;
        cS[node * 132 + u] = AP2 * c0[(size_t)(n_base + node) * D_H + u];
        hS[node * 130 + u] = f2bf_hw(h0[(size_t)(n_base + node) * D_H + u]);
    }
    // ---- mask(0): ballot + FULL list (actives then inactives; bijection) ----
    if (wave == 0) {
        int lm0 = mask[n_base + L];
        unsigned long long bm = __ballot(lm0 != 0);
        int na     = __popcll(bm);
        int below  = __popcll(bm & ((1ull << L) - 1ull));
        int belowI = __popcll((~bm) & ((1ull << L) - 1ull));
        lst[0][lm0 ? below : (na + belowI)] = (unsigned char)L;
        if (L == 0) { msk64[0] = bm; nAs[0] = na; }
    }
    __syncthreads();

// emb build for buffer B from prefetched x, mask word MN (compact rows)
#define EMB_BUILD(B, XV, MN) do {                                              \
    if (((MN) >> node_e) & 1ull) {                                             \
        int j = __popcll((MN) & ((1ull << node_e) - 1ull));                    \
        s16x8 ev;                                                              \
        _Pragma("unroll")                                                      \
        for (int jj = 0; jj < 8; jj++) {                                       \
            int e = eb * 8 + jj;                                               \
            float v = fmaf((XV).x, We_s[e], fmaf((XV).y, We_s[D_EMB + e], be_s[e])); \
            ev[jj] = (short)f2bf_hw(fmaxf(v, 0.0f));                           \
        }                                                                      \
        *(s16x8*)(&Acp[B][((j >> 4) * 6 + (eb >> 2)) * 512 + (eb & 3) * 128 + (j & 15) * 8]) = ev; \
    } } while (0)

// gather h-rows from hS into compact A buffer B using list LP (nAn rows)
#define GATHER(B, LP, NAN_) do {                                               \
    for (int j = quad; j < (NAN_); j += 4) {                                   \
        int orig = (int)(LP)[j];                                               \
        Acp[B][((j >> 4) * 6 + 2 + kbu2) * 512 + flg + (j & 15) * 8] =         \
            hS[orig * 130 + u_lane];                                           \
    } } while (0)

    // ---- build A[0]: emb(0) actives + h-row gather ----
    {
        float2 x0 = *(const float2*)(nodes + (size_t)(n_base + node_e) * 2);
        unsigned long long M0v = msk64[0];
        EMB_BUILD(0, x0, M0v);
        int nA0 = __builtin_amdgcn_readfirstlane(nAs[0]);
        GATHER(0, lst[0], nA0);
    }
    __syncthreads();

// GEMM of compact tile rt into acc slot rt&1 (C = 0, bias added in ACT)
#define GEMM_RT(rt) do {                                                       \
    {   s16x8 af0 = *(const s16x8*)(Ar + ((rt) * 6 + 0) * 512 + L * 8);        \
        _Pragma("unroll")                                                      \
        for (int g = 0; g < 4; g++)                                            \
            acc[(rt) & 1][g] = __builtin_amdgcn_mfma_f32_16x16x32_bf16(        \
                af0, Bf[g][0], (f32x4){0.f, 0.f, 0.f, 0.f}, 0, 0, 0); }        \
    _Pragma("unroll")                                                          \
    for (int kb = 1; kb < 6; kb++) {                                           \
        s16x8 af = *(const s16x8*)(Ar + ((rt) * 6 + kb) * 512 + L * 8);        \
        _Pragma("unroll")                                                      \
        for (int g = 0; g < 4; g++)                                            \
            acc[(rt) & 1][g] = __builtin_amdgcn_mfma_f32_16x16x32_bf16(        \
                af, Bf[g][kb], acc[(rt) & 1][g], 0, 0, 0); }                   \
} while (0)

// ACT for compact tile rt: all lst entries are valid node ids (<64), so every
// LDS access is in-bounds; writes only for active slots (c < nA).
#define ACT_RT(rt) do {                                                        \
    _Pragma("unroll")                                                          \
    for (int r = 0; r < 4; r++) {                                              \
        int c    = (rt) * 16 + quad * 4 + r;                                   \
        int orig = (int)lstT[c];                                               \
        float cold = cS[orig * 132 + u_lane];                                  \
        float gi = sig_pre(acc[(rt) & 1][0][r] + bias[0]);                     \
        float gf = sig_pre(acc[(rt) & 1][1][r] + bias[1]);                     \
        float rg = sig_pre(acc[(rt) & 1][2][r] + bias[2]);                     \
        float go = sig_pre(acc[(rt) & 1][3][r] + bias[3]);                     \
        float ggL = fmaf(AM4, rg, AP2);            /* 2*log2e*tanh(g) */       \
        float cnL = fmaf(gf, cold, gi * ggL);      /* 2*log2e*c_new   */       \
        float rr  = __builtin_amdgcn_rcpf(1.0f + exp2f_fast(cnL));             \
        float hv  = go * fmaf(-2.0f, rr, 1.0f);    /* o*tanh(c_new)   */       \
        unsigned short hb = f2bf_hw(hv);                                       \
        if (c < nA) {                                                          \
            cS[orig * 132 + u_lane] = cnL;                                     \
            hS[orig * 130 + u_lane] = hb;                                      \
            hNc[((rt) * 4 + kbu2) * 512 + flh + r * 8 + j_u] = hb;             \
        }                                                                      \
    } } while (0)

    unsigned long long Mp = 0;
    int nAp = 0;

    for (int t = 0; t < T_STEPS; t++) {
        unsigned short* __restrict__ Ar   = Acp[t & 1];
        unsigned short* __restrict__ hNc  = hNewC[t & 1];
        const unsigned short* __restrict__ hPv = hNewC[(t + 1) & 1]; // = (t-1)&1
        const unsigned char*  __restrict__ lstT = lst[t & 1];

        const unsigned long long M = msk64[t & 1];
        const int nA  = __builtin_amdgcn_readfirstlane(nAs[t & 1]);
        const int ntA = (nA + 15) >> 4;

        // prefetch x(t+1); wave0: ballot + FULL list build for t+1
        float2 xv = make_float2(0.0f, 0.0f);
        if (t + 1 < T_STEPS) {
            xv = *(const float2*)(nodes + ((size_t)(t + 1) * NN + n_base + node_e) * 2);
            if (wave == 0) {
                int lm = mask[(size_t)(t + 1) * NN + n_base + L];
                unsigned long long bm = __ballot(lm != 0);
                int na     = __popcll(bm);
                int below  = __popcll(bm & ((1ull << L) - 1ull));
                int belowI = __popcll((~bm) & ((1ull << L) - 1ull));
                lst[(t + 1) & 1][lm ? below : (na + belowI)] = (unsigned char)L;
                if (L == 0) { msk64[(t + 1) & 1] = bm; nAs[(t + 1) & 1] = na; }
            }
        }

        // ---- phase X: compact GEMM/ACT interleave + OPROJ(t-1) ----
        f32x4 acc[2][4];
        if (ntA > 0) GEMM_RT(0);
        if (ntA > 1) GEMM_RT(1);
        if (ntA > 0) ACT_RT(0);
        if (ntA > 2) GEMM_RT(2);
        if (ntA > 1) ACT_RT(1);
        if (ntA > 3) GEMM_RT(3);
        if (ntA > 2) ACT_RT(2);
        if (t > 0) {                       // OPROJ(t-1) over compact hNewC
            int ntP = (nAp + 15) >> 4;
            if (wave < ntP) {
                f32x4 ao = (f32x4){0.f, 0.f, 0.f, 0.f};
                #pragma unroll
                for (int kb2 = 0; kb2 < 4; kb2++) {
                    s16x8 af = *(const s16x8*)(hPv + (wave * 4 + kb2) * 512 + L * 8);
                    s16x8 wf = *(const s16x8*)(WoS + (kb2 * 64 + L) * 8);
                    ao = __builtin_amdgcn_mfma_f32_16x16x32_bf16(af, wf, ao, 0, 0, 0);
                }
                if (l15 < D_OUT) {
                    #pragma unroll
                    for (int r = 0; r < 4; r++) {
                        int c = wave * 16 + quad * 4 + r;
                        st_o[(t - 1) & 1][c * D_OUT + l15] = ao[r] + bo;
                    }
                }
            }
        }
        if (ntA > 3) ACT_RT(3);
        __syncthreads();   // barrier A

        // ---- phase Y: out-store(t-1) + build A(t+1) ----
        if (t > 0 && tid < MT * D_OUT) {
            int node = tid / D_OUT, d = tid - node * D_OUT;
            int act  = (int)((Mp >> node) & 1ull);
            int pos  = __popcll(Mp & ((1ull << node) - 1ull));
            float v  = act ? st_o[(t - 1) & 1][pos * D_OUT + d] : 0.0f;
            out[((size_t)(t - 1) * NN + n_base) * D_OUT + tid] = v;
        }
        if (t + 1 < T_STEPS) {
            unsigned long long Mn = msk64[(t + 1) & 1];
            EMB_BUILD((t + 1) & 1, xv, Mn);
            int nAn = __builtin_amdgcn_readfirstlane(nAs[(t + 1) & 1]);
            GATHER((t + 1) & 1, lst[(t + 1) & 1], nAn);
        }
        Mp = M; nAp = nA;
        __syncthreads();   // barrier B
    }

    // ---- epilogue: OPROJ(19) + store; h_fin/c_fin ----
    {
        int ntP = (nAp + 15) >> 4;
        if (wave < ntP) {
            const unsigned short* hPv = hNewC[(T_STEPS - 1) & 1];
            f32x4 ao = (f32x4){0.f, 0.f, 0.f, 0.f};
            #pragma unroll
            for (int kb2 = 0; kb2 < 4; kb2++) {
                s16x8 af = *(const s16x8*)(hPv + (wave * 4 + kb2) * 512 + L * 8);
                s16x8 wf = *(const s16x8*)(WoS + (kb2 * 64 + L) * 8);
                ao = __builtin_amdgcn_mfma_f32_16x16x32_bf16(af, wf, ao, 0, 0, 0);
            }
            if (l15 < D_OUT) {
                #pragma unroll
                for (int r = 0; r < 4; r++) {
                    int c = wave * 16 + quad * 4 + r;
                    st_o[(T_STEPS - 1) & 1][c * D_OUT + l15] = ao[r] + bo;
                }
            }
        }
    }
    __syncthreads();
    if (tid < MT * D_OUT) {
        int node = tid / D_OUT, d = tid - node * D_OUT;
        int act  = (int)((Mp >> node) & 1ull);
        int pos  = __popcll(Mp & ((1ull << node) - 1ull));
        float v  = act ? st_o[(T_STEPS - 1) & 1][pos * D_OUT + d] : 0.0f;
        out[((size_t)(T_STEPS - 1) * NN + n_base) * D_OUT + tid] = v;
    }
    for (int i = tid; i < MT * D_H; i += BLOCK) {
        int node = i >> 7, u = i & 127;
        out[OFF_H + (size_t)(n_base + node) * D_H + u] = bf2f(hS[node * 130 + u]);
        out[OFF_C + (size_t)(n_base + node) * D_H + u] = CINV * cS[node * 132 + u];
    }

#undef EMB_BUILD
#undef GATHER
#undef GEMM_RT
#undef ACT_RT
}

extern "C" void kernel_launch(void* const* d_in, const int* in_sizes, int n_in,
                              void* d_out, int out_size, void* d_ws, size_t ws_size,
                              hipStream_t stream) {
    const float* nodes   = (const float*)d_in[0];
    const int*   mask    = (const int*)  d_in[1];
    const float* h0      = (const float*)d_in[2];
    const float* c0      = (const float*)d_in[3];
    const float* W_embed = (const float*)d_in[4];
    const float* b_embed = (const float*)d_in[5];
    const float* W_ih    = (const float*)d_in[6];
    const float* b_ih    = (const float*)d_in[7];
    const float* W_hh    = (const float*)d_in[8];
    const float* b_hh    = (const float*)d_in[9];
    const float* W_out   = (const float*)d_in[10];
    const float* b_out   = (const float*)d_in[11];
    float* out = (float*)d_out;

    unsigned short* Wp    = (unsigned short*)d_ws;
    unsigned short* WoutF = Wp + WP_ELEMS;
    float*          b_sum = (float*)(WoutF + WOUT_ELEMS);

    prepack_kernel<<<(WP_ELEMS + WOUT_ELEMS + 255) / 256, 256, 0, stream>>>(
        W_ih, b_ih, W_hh, b_hh, W_out, Wp, WoutF, b_sum);

    vlstm_kernel<<<GRID, BLOCK, 0, stream>>>(
        nodes, mask, h0, c0, W_embed, b_embed, b_out, Wp, WoutF, b_sum, out);
}

// Round 11
// 270.218 us; speedup vs baseline: 1.2013x; 1.0095x over previous
//
#include <hip/hip_runtime.h>
#include <cstddef>

// ============================================================================
// VLSTM via bf16 MFMA, R15: compaction + DIRECT hS reads in GEMM (no gather).
//  - R14 post-mortem: compaction won (190.5us) but bank conflicts rose to
//    9.1M -- the GATHER pass (hS->Acp round-trip, scattered 2B writes) is
//    pure overhead. MFMA A-frag = 8 contiguous shorts of one node's h row,
//    so GEMM reads hS directly: lane base lst[rt*16+l15]*136 + quad*8,
//    immediate offset (kb-2)*64. GATHER deleted; Acp -> emb-only (16 KB).
//  - hS stride 130->136 shorts: rows 16B-aligned for ds_read_b128; start
//    bank class = orig mod 8 -> typical 2-way (free, m136).
//  - Race fix: ACT's hS writes defer to phase Y (hb held in 16 regs); cS
//    writes stay in X (column-exclusive per wave, no cross-wave sharing).
//  - Everything else = R14: 2 barriers/step, hNc dbuf for OPROJ(t-1),
//    st_o dbuf + dense out-store, ballot/popcount full-bijection lists.
// ============================================================================

typedef __attribute__((ext_vector_type(8))) short  s16x8;   // 8 x bf16
typedef __attribute__((ext_vector_type(4))) float  f32x4;

namespace {
constexpr int T_STEPS = 20;
constexpr int NN      = 32768;
constexpr int D_EMB   = 64;
constexpr int D_H     = 128;
constexpr int D_OUT   = 5;
constexpr int G4      = 512;
constexpr int MT      = 64;                   // nodes per block
constexpr int BLOCK   = 512;
constexpr int GRID    = NN / MT;              // 512 blocks, 2 rounds
constexpr int WP_ELEMS   = 8 * 4 * 6 * 64 * 8;
constexpr int WOUT_ELEMS = 4 * 64 * 8;
constexpr int HSTR    = 136;                  // hS row stride (shorts), 16B-aligned
constexpr float LOG2E = 1.4426950408889634f;
constexpr float AM4   = -4.0f * LOG2E;
constexpr float AP2   =  2.0f * LOG2E;
constexpr float CINV  = 0.34657359027997264f;   // 1/(2*log2e)
constexpr size_t OFF_H = (size_t)T_STEPS * NN * D_OUT;
constexpr size_t OFF_C = OFF_H + (size_t)NN * D_H;
}

__device__ __forceinline__ unsigned short f2bf(float x) {
    unsigned u = __float_as_uint(x);
    u = (u + 0x7FFFu + ((u >> 16) & 1u)) >> 16;     // RNE
    return (unsigned short)u;
}
__device__ __forceinline__ unsigned short f2bf_hw(float x) {
    __bf16 b = (__bf16)x;
    union { __bf16 b; unsigned short u; } cv;
    cv.b = b;
    return cv.u;
}
__device__ __forceinline__ float bf2f(unsigned short h) {
    return __uint_as_float(((unsigned)h) << 16);
}
__device__ __forceinline__ float exp2f_fast(float x) {
#if __has_builtin(__builtin_amdgcn_exp2f)
    return __builtin_amdgcn_exp2f(x);
#else
    return __expf(x * 0.6931471805599453f);
#endif
}
__device__ __forceinline__ float sig_pre(float a) {   // sigmoid, a = -x*log2e
    return __builtin_amdgcn_rcpf(1.0f + exp2f_fast(a));
}

// ----------------------------------------------------------------------------
__global__ void prepack_kernel(const float* __restrict__ W_ih,
                               const float* __restrict__ b_ih,
                               const float* __restrict__ W_hh,
                               const float* __restrict__ b_hh,
                               const float* __restrict__ W_out,
                               unsigned short* __restrict__ Wp,
                               unsigned short* __restrict__ WoutF,
                               float* __restrict__ b_sum) {
    int idx = blockIdx.x * blockDim.x + threadIdx.x;
    if (idx < WP_ELEMS) {
        int j    = idx & 7;
        int L    = (idx >> 3) & 63;
        int rest = idx >> 9;
        int kb   = rest % 6;
        int gw   = rest / 6;
        int g    = gw & 3, w = gw >> 2;
        int k    = kb * 32 + (L >> 4) * 8 + j;
        int col  = g * D_H + w * 16 + (L & 15);
        float v  = (k < D_EMB) ? W_ih[k * G4 + col] : W_hh[(k - D_EMB) * G4 + col];
        float s  = (g == 2) ? (2.0f * LOG2E) : (-LOG2E);
        Wp[idx] = f2bf(v * s);
    } else if (idx < WP_ELEMS + WOUT_ELEMS) {
        int i2 = idx - WP_ELEMS;
        int j = i2 & 7, L = (i2 >> 3) & 63, kb2 = i2 >> 9;
        int k = kb2 * 32 + (L >> 4) * 8 + j;
        int n = L & 15;
        WoutF[i2] = (n < D_OUT) ? f2bf(W_out[k * D_OUT + n]) : (unsigned short)0;
    }
    if (idx < G4) {
        int g = idx / D_H;
        float s = (g == 2) ? (2.0f * LOG2E) : (-LOG2E);
        b_sum[idx] = (b_ih[idx] + b_hh[idx]) * s;
    }
}

// ----------------------------------------------------------------------------
__global__ __launch_bounds__(BLOCK, 1) void vlstm_kernel(
    const float* __restrict__ nodes,   // [T][N][2]
    const int*   __restrict__ mask,    // [T][N]
    const float* __restrict__ h0,      // [N][128]
    const float* __restrict__ c0,      // [N][128]
    const float* __restrict__ W_embed, // [2][64]
    const float* __restrict__ b_embed, // [64]
    const float* __restrict__ b_out,   // [5]
    const unsigned short* __restrict__ Wp,
    const unsigned short* __restrict__ WoutF,
    const float* __restrict__ b_sum,
    float* __restrict__ out)
{
    __shared__ __align__(16) unsigned short E[2][4 * 2 * 512];     // 16 KB (emb)
    __shared__ __align__(16) unsigned short hNewC[2][4 * 4 * 512]; // 32 KB
    __shared__ float          cS[MT * 132];                        // 33.8 KB
    __shared__ __align__(16) unsigned short hS[MT * HSTR];         // 17.4 KB
    __shared__ float          st_o[2][MT * D_OUT];                 // 2.5 KB
    __shared__ __align__(16) unsigned short WoS[WOUT_ELEMS];       // 4 KB
    __shared__ float We_s[2 * D_EMB];
    __shared__ float be_s[D_EMB];
    __shared__ unsigned long long msk64[2];
    __shared__ unsigned char lst[2][MT];
    __shared__ int nAs[2];

    const int tid  = threadIdx.x;
    const int wave = tid >> 6;
    const int L    = tid & 63;
    const int quad = L >> 4;
    const int l15  = L & 15;
    const int n_base = blockIdx.x * MT;
    const int u_lane = wave * 16 + l15;

    // ---- gate weights -> registers, once (96 VGPR/wave) ----
    const unsigned short* wbase = Wp + (size_t)wave * (4 * 6 * 64 * 8);
    s16x8 Bf[4][6];
    #pragma unroll
    for (int g = 0; g < 4; g++)
        #pragma unroll
        for (int kb = 0; kb < 6; kb++)
            Bf[g][kb] = *(const s16x8*)(wbase + ((g * 6 + kb) * 64 + L) * 8);

    float bias[4];
    #pragma unroll
    for (int g = 0; g < 4; g++) bias[g] = b_sum[g * D_H + u_lane];
    const float bo = (l15 < D_OUT) ? b_out[l15] : 0.0f;

    // per-thread geometry: hNc writes
    const int kbu2 = u_lane >> 5;                               // h kb-block 0..3
    const int j_u  = u_lane & 7;
    const int flh  = ((u_lane >> 3) & 3) * 128 + quad * 32;     // hNewC base
    const int node_e = tid >> 3;
    const int eb     = tid & 7;

    // ---- one-time LDS staging ----
    for (int i = tid; i < 3 * D_EMB; i += BLOCK) {
        if (i < 2 * D_EMB) We_s[i] = W_embed[i];
        else               be_s[i - 2 * D_EMB] = b_embed[i - 2 * D_EMB];
    }
    for (int i = tid; i < WOUT_ELEMS; i += BLOCK) WoS[i] = WoutF[i];

    // ---- state load: cS (scaled), hS (bf16, stride 136) ----
    for (int i = tid; i < MT * D_H; i += BLOCK) {
        int node = i >> 7, u = i & 127;
        cS[node * 132 + u]  = AP2 * c0[(size_t)(n_base + node) * D_H + u];
        hS[node * HSTR + u] = f2bf_hw(h0[(size_t)(n_base + node) * D_H + u]);
    }
    // ---- mask(0): ballot + FULL list (actives then inactives; bijection) ----
    if (wave == 0) {
        int lm0 = mask[n_base + L];
        unsigned long long bm = __ballot(lm0 != 0);
        int na     = __popcll(bm);
        int below  = __popcll(bm & ((1ull << L) - 1ull));
        int belowI = __popcll((~bm) & ((1ull << L) - 1ull));
        lst[0][lm0 ? below : (na + belowI)] = (unsigned char)L;
        if (L == 0) { msk64[0] = bm; nAs[0] = na; }
    }
    __syncthreads();

// emb build for buffer B from prefetched x, mask word MN (compact rows)
#define EMB_BUILD(B, XV, MN) do {                                              \
    if (((MN) >> node_e) & 1ull) {                                             \
        int j = __popcll((MN) & ((1ull << node_e) - 1ull));                    \
        s16x8 ev;                                                              \
        _Pragma("unroll")                                                      \
        for (int jj = 0; jj < 8; jj++) {                                       \
            int e = eb * 8 + jj;                                               \
            float v = fmaf((XV).x, We_s[e], fmaf((XV).y, We_s[D_EMB + e], be_s[e])); \
            ev[jj] = (short)f2bf_hw(fmaxf(v, 0.0f));                           \
        }                                                                      \
        *(s16x8*)(&E[B][((j >> 4) * 2 + (eb >> 2)) * 512 + (eb & 3) * 128 + (j & 15) * 8]) = ev; \
    } } while (0)

    // ---- build E[0]: emb(0) actives ----
    {
        float2 x0 = *(const float2*)(nodes + (size_t)(n_base + node_e) * 2);
        unsigned long long M0v = msk64[0];
        EMB_BUILD(0, x0, M0v);
    }
    __syncthreads();

// GEMM of compact tile rt into acc slot rt&1. kb 0-1 from E (emb, compact);
// kb 2-5 DIRECT from hS: per-lane row base via lst, immediate kb offsets.
#define GEMM_RT(rt) do {                                                       \
    int og = (int)lstT[(rt) * 16 + l15];                                       \
    const unsigned short* hrow = hS + og * HSTR + quad * 8;                    \
    {   s16x8 af0 = *(const s16x8*)(Er + ((rt) * 2 + 0) * 512 + L * 8);        \
        _Pragma("unroll")                                                      \
        for (int g = 0; g < 4; g++)                                            \
            acc[(rt) & 1][g] = __builtin_amdgcn_mfma_f32_16x16x32_bf16(        \
                af0, Bf[g][0], (f32x4){0.f, 0.f, 0.f, 0.f}, 0, 0, 0); }        \
    {   s16x8 af1 = *(const s16x8*)(Er + ((rt) * 2 + 1) * 512 + L * 8);        \
        _Pragma("unroll")                                                      \
        for (int g = 0; g < 4; g++)                                            \
            acc[(rt) & 1][g] = __builtin_amdgcn_mfma_f32_16x16x32_bf16(        \
                af1, Bf[g][1], acc[(rt) & 1][g], 0, 0, 0); }                   \
    _Pragma("unroll")                                                          \
    for (int kb = 2; kb < 6; kb++) {                                           \
        s16x8 af = *(const s16x8*)(hrow + (kb - 2) * 32);                      \
        _Pragma("unroll")                                                      \
        for (int g = 0; g < 4; g++)                                            \
            acc[(rt) & 1][g] = __builtin_amdgcn_mfma_f32_16x16x32_bf16(        \
                af, Bf[g][kb], acc[(rt) & 1][g], 0, 0, 0); }                   \
} while (0)

// ACT for compact tile rt: reads/writes cS (column-exclusive per wave, safe
// in X); hS writes DEFERRED to Y via hbv regs; hNc written here (dbuf).
#define ACT_RT(rt) do {                                                        \
    _Pragma("unroll")                                                          \
    for (int r = 0; r < 4; r++) {                                              \
        int c    = (rt) * 16 + quad * 4 + r;                                   \
        int orig = (int)lstT[c];                                               \
        float cold = cS[orig * 132 + u_lane];                                  \
        float gi = sig_pre(acc[(rt) & 1][0][r] + bias[0]);                     \
        float gf = sig_pre(acc[(rt) & 1][1][r] + bias[1]);                     \
        float rg = sig_pre(acc[(rt) & 1][2][r] + bias[2]);                     \
        float go = sig_pre(acc[(rt) & 1][3][r] + bias[3]);                     \
        float ggL = fmaf(AM4, rg, AP2);            /* 2*log2e*tanh(g) */       \
        float cnL = fmaf(gf, cold, gi * ggL);      /* 2*log2e*c_new   */       \
        float rr  = __builtin_amdgcn_rcpf(1.0f + exp2f_fast(cnL));             \
        float hv  = go * fmaf(-2.0f, rr, 1.0f);    /* o*tanh(c_new)   */       \
        unsigned short hb = f2bf_hw(hv);                                       \
        hbv[rt][r] = hb;                                                       \
        if (c < nA) {                                                          \
            cS[orig * 132 + u_lane] = cnL;                                     \
            hNc[((rt) * 4 + kbu2) * 512 + flh + r * 8 + j_u] = hb;             \
        }                                                                      \
    } } while (0)

    unsigned long long Mp = 0;
    int nAp = 0;

    for (int t = 0; t < T_STEPS; t++) {
        unsigned short* __restrict__ Er   = E[t & 1];
        unsigned short* __restrict__ hNc  = hNewC[t & 1];
        const unsigned short* __restrict__ hPv = hNewC[(t + 1) & 1]; // = (t-1)&1
        const unsigned char*  __restrict__ lstT = lst[t & 1];

        const unsigned long long M = msk64[t & 1];
        const int nA  = __builtin_amdgcn_readfirstlane(nAs[t & 1]);
        const int ntA = (nA + 15) >> 4;

        // prefetch x(t+1); wave0: ballot + FULL list build for t+1
        float2 xv = make_float2(0.0f, 0.0f);
        if (t + 1 < T_STEPS) {
            xv = *(const float2*)(nodes + ((size_t)(t + 1) * NN + n_base + node_e) * 2);
            if (wave == 0) {
                int lm = mask[(size_t)(t + 1) * NN + n_base + L];
                unsigned long long bm = __ballot(lm != 0);
                int na     = __popcll(bm);
                int below  = __popcll(bm & ((1ull << L) - 1ull));
                int belowI = __popcll((~bm) & ((1ull << L) - 1ull));
                lst[(t + 1) & 1][lm ? below : (na + belowI)] = (unsigned char)L;
                if (L == 0) { msk64[(t + 1) & 1] = bm; nAs[(t + 1) & 1] = na; }
            }
        }

        // ---- phase X: compact GEMM/ACT interleave + OPROJ(t-1) ----
        f32x4 acc[2][4];
        unsigned short hbv[4][4];
        if (ntA > 0) GEMM_RT(0);
        if (ntA > 1) GEMM_RT(1);
        if (ntA > 0) ACT_RT(0);
        if (ntA > 2) GEMM_RT(2);
        if (ntA > 1) ACT_RT(1);
        if (ntA > 3) GEMM_RT(3);
        if (ntA > 2) ACT_RT(2);
        if (t > 0) {                       // OPROJ(t-1) over compact hNewC
            int ntP = (nAp + 15) >> 4;
            if (wave < ntP) {
                f32x4 ao = (f32x4){0.f, 0.f, 0.f, 0.f};
                #pragma unroll
                for (int kb2 = 0; kb2 < 4; kb2++) {
                    s16x8 af = *(const s16x8*)(hPv + (wave * 4 + kb2) * 512 + L * 8);
                    s16x8 wf = *(const s16x8*)(WoS + (kb2 * 64 + L) * 8);
                    ao = __builtin_amdgcn_mfma_f32_16x16x32_bf16(af, wf, ao, 0, 0, 0);
                }
                if (l15 < D_OUT) {
                    #pragma unroll
                    for (int r = 0; r < 4; r++) {
                        int c = wave * 16 + quad * 4 + r;
                        st_o[(t - 1) & 1][c * D_OUT + l15] = ao[r] + bo;
                    }
                }
            }
        }
        if (ntA > 3) ACT_RT(3);
        __syncthreads();   // barrier A: ACT hS-read phase done; st_o ready

        // ---- phase Y: deferred hS writes + out-store(t-1) + emb(t+1) ----
        #pragma unroll
        for (int rt = 0; rt < 4; rt++)
            #pragma unroll
            for (int r = 0; r < 4; r++) {
                int c = rt * 16 + quad * 4 + r;
                if (c < nA) hS[(int)lstT[c] * HSTR + u_lane] = hbv[rt][r];
            }
        if (t > 0 && tid < MT * D_OUT) {
            int node = tid / D_OUT, d = tid - node * D_OUT;
            int act  = (int)((Mp >> node) & 1ull);
            int pos  = __popcll(Mp & ((1ull << node) - 1ull));
            float v  = act ? st_o[(t - 1) & 1][pos * D_OUT + d] : 0.0f;
            out[((size_t)(t - 1) * NN + n_base) * D_OUT + tid] = v;
        }
        if (t + 1 < T_STEPS) {
            unsigned long long Mn = msk64[(t + 1) & 1];
            EMB_BUILD((t + 1) & 1, xv, Mn);
        }
        Mp = M; nAp = nA;
        __syncthreads();   // barrier B: hS/E/lst ready for step t+1
    }

    // ---- epilogue: OPROJ(19) + store; h_fin/c_fin ----
    {
        int ntP = (nAp + 15) >> 4;
        if (wave < ntP) {
            const unsigned short* hPv = hNewC[(T_STEPS - 1) & 1];
            f32x4 ao = (f32x4){0.f, 0.f, 0.f, 0.f};
            #pragma unroll
            for (int kb2 = 0; kb2 < 4; kb2++) {
                s16x8 af = *(const s16x8*)(hPv + (wave * 4 + kb2) * 512 + L * 8);
                s16x8 wf = *(const s16x8*)(WoS + (kb2 * 64 + L) * 8);
                ao = __builtin_amdgcn_mfma_f32_16x16x32_bf16(af, wf, ao, 0, 0, 0);
            }
            if (l15 < D_OUT) {
                #pragma unroll
                for (int r = 0; r < 4; r++) {
                    int c = wave * 16 + quad * 4 + r;
                    st_o[(T_STEPS - 1) & 1][c * D_OUT + l15] = ao[r] + bo;
                }
            }
        }
    }
    __syncthreads();
    if (tid < MT * D_OUT) {
        int node = tid / D_OUT, d = tid - node * D_OUT;
        int act  = (int)((Mp >> node) & 1ull);
        int pos  = __popcll(Mp & ((1ull << node) - 1ull));
        float v  = act ? st_o[(T_STEPS - 1) & 1][pos * D_OUT + d] : 0.0f;
        out[((size_t)(T_STEPS - 1) * NN + n_base) * D_OUT + tid] = v;
    }
    for (int i = tid; i < MT * D_H; i += BLOCK) {
        int node = i >> 7, u = i & 127;
        out[OFF_H + (size_t)(n_base + node) * D_H + u] = bf2f(hS[node * HSTR + u]);
        out[OFF_C + (size_t)(n_base + node) * D_H + u] = CINV * cS[node * 132 + u];
    }

#undef EMB_BUILD
#undef GEMM_RT
#undef ACT_RT
}

extern "C" void kernel_launch(void* const* d_in, const int* in_sizes, int n_in,
                              void* d_out, int out_size, void* d_ws, size_t ws_size,
                              hipStream_t stream) {
    const float* nodes   = (const float*)d_in[0];
    const int*   mask    = (const int*)  d_in[1];
    const float* h0      = (const float*)d_in[2];
    const float* c0      = (const float*)d_in[3];
    const float* W_embed = (const float*)d_in[4];
    const float* b_embed = (const float*)d_in[5];
    const float* W_ih    = (const float*)d_in[6];
    const float* b_ih    = (const float*)d_in[7];
    const float* W_hh    = (const float*)d_in[8];
    const float* b_hh    = (const float*)d_in[9];
    const float* W_out   = (const float*)d_in[10];
    const float* b_out   = (const float*)d_in[11];
    float* out = (float*)d_out;

    unsigned short* Wp    = (unsigned short*)d_ws;
    unsigned short* WoutF = Wp + WP_ELEMS;
    float*          b_sum = (float*)(WoutF + WOUT_ELEMS);

    prepack_kernel<<<(WP_ELEMS + WOUT_ELEMS + 255) / 256, 256, 0, stream>>>(
        W_ih, b_ih, W_hh, b_hh, W_out, Wp, WoutF, b_sum);

    vlstm_kernel<<<GRID, BLOCK, 0, stream>>>(
        nodes, mask, h0, c0, W_embed, b_embed, b_out, Wp, WoutF, b_sum, out);
}

// Round 12
// 267.506 us; speedup vs baseline: 1.2134x; 1.0101x over previous
//
#include <hip/hip_runtime.h>
#include <cstddef>

// ============================================================================
// VLSTM via bf16 MFMA, R16: R15 minus hNewC -- OPROJ reads h directly from hS.
//  - Insight: during phase X of step t, hS holds exactly h(t-1) (hS writes
//    are deferred to phase Y). OPROJ(t-1) can read its A-frags straight from
//    hS with the same per-lane-row pattern GEMM uses, via the PREVIOUS active
//    list. hNewC (32 KB + 16 scattered 2B writes/thread/step) deleted.
//  - lst/msk64/nAs triple-buffered: build (t+1)%3 | GEMM reads t%3 | OPROJ
//    reads (t+2)%3 -- pairwise distinct mod 3, no race with wave0's build.
//  - hbv packed 2x16b -> hbp[4][2] (8 VGPR, static unroll indexing).
//  - Occupancy note: 2 co-resident 512-blocks would need <=128 unified regs
//    (weights 96 + acc 32 + temps ~= 152) -- impossible; LDS drop is for DS
//    traffic, not occupancy. launch_bounds stays (512,1) (R10/R12 lesson).
// ============================================================================

typedef __attribute__((ext_vector_type(8))) short  s16x8;   // 8 x bf16
typedef __attribute__((ext_vector_type(4))) float  f32x4;

namespace {
constexpr int T_STEPS = 20;
constexpr int NN      = 32768;
constexpr int D_EMB   = 64;
constexpr int D_H     = 128;
constexpr int D_OUT   = 5;
constexpr int G4      = 512;
constexpr int MT      = 64;                   // nodes per block
constexpr int BLOCK   = 512;
constexpr int GRID    = NN / MT;              // 512 blocks, 2 rounds
constexpr int WP_ELEMS   = 8 * 4 * 6 * 64 * 8;
constexpr int WOUT_ELEMS = 4 * 64 * 8;
constexpr int HSTR    = 136;                  // hS row stride (shorts), 16B-aligned
constexpr float LOG2E = 1.4426950408889634f;
constexpr float AM4   = -4.0f * LOG2E;
constexpr float AP2   =  2.0f * LOG2E;
constexpr float CINV  = 0.34657359027997264f;   // 1/(2*log2e)
constexpr size_t OFF_H = (size_t)T_STEPS * NN * D_OUT;
constexpr size_t OFF_C = OFF_H + (size_t)NN * D_H;
}

__device__ __forceinline__ unsigned short f2bf(float x) {
    unsigned u = __float_as_uint(x);
    u = (u + 0x7FFFu + ((u >> 16) & 1u)) >> 16;     // RNE
    return (unsigned short)u;
}
__device__ __forceinline__ unsigned short f2bf_hw(float x) {
    __bf16 b = (__bf16)x;
    union { __bf16 b; unsigned short u; } cv;
    cv.b = b;
    return cv.u;
}
__device__ __forceinline__ float bf2f(unsigned short h) {
    return __uint_as_float(((unsigned)h) << 16);
}
__device__ __forceinline__ float exp2f_fast(float x) {
#if __has_builtin(__builtin_amdgcn_exp2f)
    return __builtin_amdgcn_exp2f(x);
#else
    return __expf(x * 0.6931471805599453f);
#endif
}
__device__ __forceinline__ float sig_pre(float a) {   // sigmoid, a = -x*log2e
    return __builtin_amdgcn_rcpf(1.0f + exp2f_fast(a));
}

// ----------------------------------------------------------------------------
__global__ void prepack_kernel(const float* __restrict__ W_ih,
                               const float* __restrict__ b_ih,
                               const float* __restrict__ W_hh,
                               const float* __restrict__ b_hh,
                               const float* __restrict__ W_out,
                               unsigned short* __restrict__ Wp,
                               unsigned short* __restrict__ WoutF,
                               float* __restrict__ b_sum) {
    int idx = blockIdx.x * blockDim.x + threadIdx.x;
    if (idx < WP_ELEMS) {
        int j    = idx & 7;
        int L    = (idx >> 3) & 63;
        int rest = idx >> 9;
        int kb   = rest % 6;
        int gw   = rest / 6;
        int g    = gw & 3, w = gw >> 2;
        int k    = kb * 32 + (L >> 4) * 8 + j;
        int col  = g * D_H + w * 16 + (L & 15);
        float v  = (k < D_EMB) ? W_ih[k * G4 + col] : W_hh[(k - D_EMB) * G4 + col];
        float s  = (g == 2) ? (2.0f * LOG2E) : (-LOG2E);
        Wp[idx] = f2bf(v * s);
    } else if (idx < WP_ELEMS + WOUT_ELEMS) {
        int i2 = idx - WP_ELEMS;
        int j = i2 & 7, L = (i2 >> 3) & 63, kb2 = i2 >> 9;
        int k = kb2 * 32 + (L >> 4) * 8 + j;
        int n = L & 15;
        WoutF[i2] = (n < D_OUT) ? f2bf(W_out[k * D_OUT + n]) : (unsigned short)0;
    }
    if (idx < G4) {
        int g = idx / D_H;
        float s = (g == 2) ? (2.0f * LOG2E) : (-LOG2E);
        b_sum[idx] = (b_ih[idx] + b_hh[idx]) * s;
    }
}

// ----------------------------------------------------------------------------
__global__ __launch_bounds__(BLOCK, 1) void vlstm_kernel(
    const float* __restrict__ nodes,   // [T][N][2]
    const int*   __restrict__ mask,    // [T][N]
    const float* __restrict__ h0,      // [N][128]
    const float* __restrict__ c0,      // [N][128]
    const float* __restrict__ W_embed, // [2][64]
    const float* __restrict__ b_embed, // [64]
    const float* __restrict__ b_out,   // [5]
    const unsigned short* __restrict__ Wp,
    const unsigned short* __restrict__ WoutF,
    const float* __restrict__ b_sum,
    float* __restrict__ out)
{
    __shared__ __align__(16) unsigned short E[2][4 * 2 * 512];     // 16 KB (emb)
    __shared__ float          cS[MT * 132];                        // 33.8 KB
    __shared__ __align__(16) unsigned short hS[MT * HSTR];         // 17.4 KB
    __shared__ float          st_o[2][MT * D_OUT];                 // 2.5 KB
    __shared__ __align__(16) unsigned short WoS[WOUT_ELEMS];       // 4 KB
    __shared__ float We_s[2 * D_EMB];
    __shared__ float be_s[D_EMB];
    __shared__ unsigned long long msk64[3];
    __shared__ unsigned char lst[3][MT];
    __shared__ int nAs[3];

    const int tid  = threadIdx.x;
    const int wave = tid >> 6;
    const int L    = tid & 63;
    const int quad = L >> 4;
    const int l15  = L & 15;
    const int n_base = blockIdx.x * MT;
    const int u_lane = wave * 16 + l15;

    // ---- gate weights -> registers, once (96 VGPR/wave) ----
    const unsigned short* wbase = Wp + (size_t)wave * (4 * 6 * 64 * 8);
    s16x8 Bf[4][6];
    #pragma unroll
    for (int g = 0; g < 4; g++)
        #pragma unroll
        for (int kb = 0; kb < 6; kb++)
            Bf[g][kb] = *(const s16x8*)(wbase + ((g * 6 + kb) * 64 + L) * 8);

    float bias[4];
    #pragma unroll
    for (int g = 0; g < 4; g++) bias[g] = b_sum[g * D_H + u_lane];
    const float bo = (l15 < D_OUT) ? b_out[l15] : 0.0f;

    const int node_e = tid >> 3;
    const int eb     = tid & 7;

    // ---- one-time LDS staging ----
    for (int i = tid; i < 3 * D_EMB; i += BLOCK) {
        if (i < 2 * D_EMB) We_s[i] = W_embed[i];
        else               be_s[i - 2 * D_EMB] = b_embed[i - 2 * D_EMB];
    }
    for (int i = tid; i < WOUT_ELEMS; i += BLOCK) WoS[i] = WoutF[i];

    // ---- state load: cS (scaled), hS (bf16, stride 136) ----
    for (int i = tid; i < MT * D_H; i += BLOCK) {
        int node = i >> 7, u = i & 127;
        cS[node * 132 + u]  = AP2 * c0[(size_t)(n_base + node) * D_H + u];
        hS[node * HSTR + u] = f2bf_hw(h0[(size_t)(n_base + node) * D_H + u]);
    }
    // ---- mask(0): ballot + FULL list (actives then inactives; bijection) ----
    if (wave == 0) {
        int lm0 = mask[n_base + L];
        unsigned long long bm = __ballot(lm0 != 0);
        int na     = __popcll(bm);
        int below  = __popcll(bm & ((1ull << L) - 1ull));
        int belowI = __popcll((~bm) & ((1ull << L) - 1ull));
        lst[0][lm0 ? below : (na + belowI)] = (unsigned char)L;
        if (L == 0) { msk64[0] = bm; nAs[0] = na; }
    }
    __syncthreads();

// emb build for buffer B from prefetched x, mask word MN (compact rows)
#define EMB_BUILD(B, XV, MN) do {                                              \
    if (((MN) >> node_e) & 1ull) {                                             \
        int j = __popcll((MN) & ((1ull << node_e) - 1ull));                    \
        s16x8 ev;                                                              \
        _Pragma("unroll")                                                      \
        for (int jj = 0; jj < 8; jj++) {                                       \
            int e = eb * 8 + jj;                                               \
            float v = fmaf((XV).x, We_s[e], fmaf((XV).y, We_s[D_EMB + e], be_s[e])); \
            ev[jj] = (short)f2bf_hw(fmaxf(v, 0.0f));                           \
        }                                                                      \
        *(s16x8*)(&E[B][((j >> 4) * 2 + (eb >> 2)) * 512 + (eb & 3) * 128 + (j & 15) * 8]) = ev; \
    } } while (0)

    // ---- build E[0]: emb(0) actives ----
    {
        float2 x0 = *(const float2*)(nodes + (size_t)(n_base + node_e) * 2);
        unsigned long long M0v = msk64[0];
        EMB_BUILD(0, x0, M0v);
    }
    __syncthreads();

// GEMM of compact tile rt into acc slot rt&1. kb 0-1 from E (emb, compact);
// kb 2-5 DIRECT from hS: per-lane row base via lst, immediate kb offsets.
#define GEMM_RT(rt) do {                                                       \
    int og = (int)lstT[(rt) * 16 + l15];                                       \
    const unsigned short* hrow = hS + og * HSTR + quad * 8;                    \
    {   s16x8 af0 = *(const s16x8*)(Er + ((rt) * 2 + 0) * 512 + L * 8);        \
        _Pragma("unroll")                                                      \
        for (int g = 0; g < 4; g++)                                            \
            acc[(rt) & 1][g] = __builtin_amdgcn_mfma_f32_16x16x32_bf16(        \
                af0, Bf[g][0], (f32x4){0.f, 0.f, 0.f, 0.f}, 0, 0, 0); }        \
    {   s16x8 af1 = *(const s16x8*)(Er + ((rt) * 2 + 1) * 512 + L * 8);        \
        _Pragma("unroll")                                                      \
        for (int g = 0; g < 4; g++)                                            \
            acc[(rt) & 1][g] = __builtin_amdgcn_mfma_f32_16x16x32_bf16(        \
                af1, Bf[g][1], acc[(rt) & 1][g], 0, 0, 0); }                   \
    _Pragma("unroll")                                                          \
    for (int kb = 2; kb < 6; kb++) {                                           \
        s16x8 af = *(const s16x8*)(hrow + (kb - 2) * 32);                      \
        _Pragma("unroll")                                                      \
        for (int g = 0; g < 4; g++)                                            \
            acc[(rt) & 1][g] = __builtin_amdgcn_mfma_f32_16x16x32_bf16(        \
                af, Bf[g][kb], acc[(rt) & 1][g], 0, 0, 0); }                   \
} while (0)

// ACT for compact tile rt: reads/writes cS (cell-exclusive, safe in X);
// hS writes DEFERRED to Y via packed hbp regs (static unroll indexing).
#define ACT_RT(rt) do {                                                        \
    _Pragma("unroll")                                                          \
    for (int r = 0; r < 4; r++) {                                              \
        int c    = (rt) * 16 + quad * 4 + r;                                   \
        int orig = (int)lstT[c];                                               \
        float cold = cS[orig * 132 + u_lane];                                  \
        float gi = sig_pre(acc[(rt) & 1][0][r] + bias[0]);                     \
        float gf = sig_pre(acc[(rt) & 1][1][r] + bias[1]);                     \
        float rg = sig_pre(acc[(rt) & 1][2][r] + bias[2]);                     \
        float go = sig_pre(acc[(rt) & 1][3][r] + bias[3]);                     \
        float ggL = fmaf(AM4, rg, AP2);            /* 2*log2e*tanh(g) */       \
        float cnL = fmaf(gf, cold, gi * ggL);      /* 2*log2e*c_new   */       \
        float rr  = __builtin_amdgcn_rcpf(1.0f + exp2f_fast(cnL));             \
        float hv  = go * fmaf(-2.0f, rr, 1.0f);    /* o*tanh(c_new)   */       \
        unsigned hb = (unsigned)f2bf_hw(hv);                                   \
        if (r & 1) hbp[rt][r >> 1] |= hb << 16;                                \
        else       hbp[rt][r >> 1]  = hb;                                      \
        if (c < nA) cS[orig * 132 + u_lane] = cnL;                             \
    } } while (0)

// OPROJ for step TIDX: A-frags DIRECT from hS (holds h(TIDX) during this
// phase), rows via list LSTP. Result -> st_o[TIDX&1].
#define OPROJ(LSTP, TIDX) do {                                                 \
    int ogp = (int)(LSTP)[wave * 16 + l15];                                    \
    const unsigned short* hrp = hS + ogp * HSTR + quad * 8;                    \
    f32x4 ao = (f32x4){0.f, 0.f, 0.f, 0.f};                                    \
    _Pragma("unroll")                                                          \
    for (int kb2 = 0; kb2 < 4; kb2++) {                                        \
        s16x8 af = *(const s16x8*)(hrp + kb2 * 32);                            \
        s16x8 wf = *(const s16x8*)(WoS + (kb2 * 64 + L) * 8);                  \
        ao = __builtin_amdgcn_mfma_f32_16x16x32_bf16(af, wf, ao, 0, 0, 0);     \
    }                                                                          \
    if (l15 < D_OUT) {                                                         \
        _Pragma("unroll")                                                      \
        for (int r = 0; r < 4; r++) {                                          \
            int c = wave * 16 + quad * 4 + r;                                  \
            st_o[(TIDX) & 1][c * D_OUT + l15] = ao[r] + bo;                    \
        }                                                                      \
    } } while (0)

    unsigned long long Mp = 0;
    int nAp = 0;

    for (int t = 0; t < T_STEPS; t++) {
        unsigned short* __restrict__ Er = E[t & 1];
        const unsigned char* __restrict__ lstT = lst[t % 3];
        const unsigned char* __restrict__ lstP = lst[(t + 2) % 3];   // t-1

        const unsigned long long M = msk64[t % 3];
        const int nA  = __builtin_amdgcn_readfirstlane(nAs[t % 3]);
        const int ntA = (nA + 15) >> 4;

        // prefetch x(t+1); wave0: ballot + FULL list build into (t+1)%3
        float2 xv = make_float2(0.0f, 0.0f);
        if (t + 1 < T_STEPS) {
            xv = *(const float2*)(nodes + ((size_t)(t + 1) * NN + n_base + node_e) * 2);
            if (wave == 0) {
                int lm = mask[(size_t)(t + 1) * NN + n_base + L];
                unsigned long long bm = __ballot(lm != 0);
                int na     = __popcll(bm);
                int below  = __popcll(bm & ((1ull << L) - 1ull));
                int belowI = __popcll((~bm) & ((1ull << L) - 1ull));
                lst[(t + 1) % 3][lm ? below : (na + belowI)] = (unsigned char)L;
                if (L == 0) { msk64[(t + 1) % 3] = bm; nAs[(t + 1) % 3] = na; }
            }
        }

        // ---- phase X: compact GEMM/ACT interleave + OPROJ(t-1) from hS ----
        f32x4 acc[2][4];
        unsigned hbp[4][2];
        if (ntA > 0) GEMM_RT(0);
        if (ntA > 1) GEMM_RT(1);
        if (ntA > 0) ACT_RT(0);
        if (ntA > 2) GEMM_RT(2);
        if (ntA > 1) ACT_RT(1);
        if (ntA > 3) GEMM_RT(3);
        if (ntA > 2) ACT_RT(2);
        if (t > 0) {
            int ntP = (nAp + 15) >> 4;
            if (wave < ntP) OPROJ(lstP, t - 1);
        }
        if (ntA > 3) ACT_RT(3);
        __syncthreads();   // barrier A: all hS reads (GEMM+OPROJ) done

        // ---- phase Y: deferred hS writes + out-store(t-1) + emb(t+1) ----
        #pragma unroll
        for (int rt = 0; rt < 4; rt++)
            #pragma unroll
            for (int r2 = 0; r2 < 2; r2++) {
                int c0 = rt * 16 + quad * 4 + r2 * 2;
                unsigned pk = hbp[rt][r2];
                if (c0 < nA)
                    hS[(int)lstT[c0] * HSTR + u_lane] = (unsigned short)(pk & 0xFFFFu);
                if (c0 + 1 < nA)
                    hS[(int)lstT[c0 + 1] * HSTR + u_lane] = (unsigned short)(pk >> 16);
            }
        if (t > 0 && tid < MT * D_OUT) {
            int node = tid / D_OUT, d = tid - node * D_OUT;
            int act  = (int)((Mp >> node) & 1ull);
            int pos  = __popcll(Mp & ((1ull << node) - 1ull));
            float v  = act ? st_o[(t - 1) & 1][pos * D_OUT + d] : 0.0f;
            out[((size_t)(t - 1) * NN + n_base) * D_OUT + tid] = v;
        }
        if (t + 1 < T_STEPS) {
            unsigned long long Mn = msk64[(t + 1) % 3];
            EMB_BUILD((t + 1) & 1, xv, Mn);
        }
        Mp = M; nAp = nA;
        __syncthreads();   // barrier B: hS/E/lst ready for step t+1
    }

    // ---- epilogue: OPROJ(19) from hS (= h(19)) + store; h_fin/c_fin ----
    {
        const unsigned char* __restrict__ lstE = lst[(T_STEPS - 1) % 3];
        int ntP = (nAp + 15) >> 4;
        if (wave < ntP) OPROJ(lstE, T_STEPS - 1);
    }
    __syncthreads();
    if (tid < MT * D_OUT) {
        int node = tid / D_OUT, d = tid - node * D_OUT;
        int act  = (int)((Mp >> node) & 1ull);
        int pos  = __popcll(Mp & ((1ull << node) - 1ull));
        float v  = act ? st_o[(T_STEPS - 1) & 1][pos * D_OUT + d] : 0.0f;
        out[((size_t)(T_STEPS - 1) * NN + n_base) * D_OUT + tid] = v;
    }
    for (int i = tid; i < MT * D_H; i += BLOCK) {
        int node = i >> 7, u = i & 127;
        out[OFF_H + (size_t)(n_base + node) * D_H + u] = bf2f(hS[node * HSTR + u]);
        out[OFF_C + (size_t)(n_base + node) * D_H + u] = CINV * cS[node * 132 + u];
    }

#undef EMB_BUILD
#undef GEMM_RT
#undef ACT_RT
#undef OPROJ
}

extern "C" void kernel_launch(void* const* d_in, const int* in_sizes, int n_in,
                              void* d_out, int out_size, void* d_ws, size_t ws_size,
                              hipStream_t stream) {
    const float* nodes   = (const float*)d_in[0];
    const int*   mask    = (const int*)  d_in[1];
    const float* h0      = (const float*)d_in[2];
    const float* c0      = (const float*)d_in[3];
    const float* W_embed = (const float*)d_in[4];
    const float* b_embed = (const float*)d_in[5];
    const float* W_ih    = (const float*)d_in[6];
    const float* b_ih    = (const float*)d_in[7];
    const float* W_hh    = (const float*)d_in[8];
    const float* b_hh    = (const float*)d_in[9];
    const float* W_out   = (const float*)d_in[10];
    const float* b_out   = (const float*)d_in[11];
    float* out = (float*)d_out;

    unsigned short* Wp    = (unsigned short*)d_ws;
    unsigned short* WoutF = Wp + WP_ELEMS;
    float*          b_sum = (float*)(WoutF + WOUT_ELEMS);

    prepack_kernel<<<(WP_ELEMS + WOUT_ELEMS + 255) / 256, 256, 0, stream>>>(
        W_ih, b_ih, W_hh, b_hh, W_out, Wp, WoutF, b_sum);

    vlstm_kernel<<<GRID, BLOCK, 0, stream>>>(
        nodes, mask, h0, c0, W_embed, b_embed, b_out, Wp, WoutF, b_sum, out);
}